// Round 13
// baseline (381.261 us; speedup 1.0000x reference)
//
#include <hip/hip_runtime.h>

#define MAX_ITER 8192
#define NCHUNK   64
#define NCHUNKS  128          // MAX_ITER / NCHUNK
#define NSCAN    64           // scanner blocks, 1 sample each
#define NTHREADS 512
#define NWAVES   8
#define TPW      8            // t's per wave in scan/fold phases

typedef unsigned long long u64;
#define KEY_MAX  0xffffffffffffffffull
#define POISON64 0xAAAAAAAAAAAAAAAAull   // d_ws re-poison pattern (0xAA bytes)

// IEEE fp32 ops, contraction off -> bitwise numpy match (verified many rounds).
__device__ __forceinline__ float mul_rn(float a, float b) {
#pragma clang fp contract(off)
  return a * b;
}
__device__ __forceinline__ float add_rn(float a, float b) {
#pragma clang fp contract(off)
  return a + b;
}
__device__ __forceinline__ float sub_rn(float a, float b) {
#pragma clang fp contract(off)
  return a - b;
}
__device__ __forceinline__ float dist2_rn(float px, float py, float sx, float sy) {
  const float dx = sub_rn(px, sx), dy = sub_rn(py, sy);
  return add_rn(mul_rn(dx, dx), mul_rn(dy, dy));
}
__device__ __forceinline__ float bcastf(float v, int lane) {
  return __int_as_float(__builtin_amdgcn_readlane(__float_as_int(v), lane));
}
__device__ __forceinline__ float bpermf(int srcByte, float v) {
  return __int_as_float(__builtin_amdgcn_ds_bpermute(srcByte, __float_as_int(v)));
}
__device__ __forceinline__ void st_agent(u64* p, u64 v) {
  __hip_atomic_store(p, v, __ATOMIC_RELAXED, __HIP_MEMORY_SCOPE_AGENT);
}
__device__ __forceinline__ u64 ld_agent(u64* p) {
  return __hip_atomic_load(p, __ATOMIC_RELAXED, __HIP_MEMORY_SCOPE_AGENT);
}
__device__ __forceinline__ u64 packf2(float x, float y) {
  return ((u64)__float_as_uint(y) << 32) | (u64)__float_as_uint(x);
}
__device__ __forceinline__ float lo32f(u64 v) {
  return __uint_as_float((unsigned)(v & 0xffffffffu));
}
__device__ __forceinline__ float hi32f(u64 v) {
  return __uint_as_float((unsigned)(v >> 32));
}
__device__ __forceinline__ void compiler_fence() {
  asm volatile("" ::: "memory");
}
// Exact (d2, idx) lex key: d2>=0 -> bit-monotone; ties -> lowest idx.
// Scanner keys carry a tag in bits 13..20 (132..255); coordinator strips it
// before comparison.  0xAA poison -> tag 85, can never false-match.
__device__ __forceinline__ u64 mkkey(float d2, int idx) {
  return ((u64)__float_as_uint(d2) << 32) | (u64)(unsigned)idx;
}
__device__ __forceinline__ unsigned tagof(u64 kv) {
  return ((unsigned)(kv >> 13)) & 0xFFu;
}
__device__ __forceinline__ void load_sample(const float* __restrict__ u,
                                            const float* __restrict__ r,
                                            float gx, float gy, int idx,
                                            float& ox, float& oy) {
  const float uu = u[idx];
  if (uu < 0.1f) { ox = gx; oy = gy; }
  else { ox = mul_rn(r[2 * idx], 200.0f); oy = mul_rn(r[2 * idx + 1], 200.0f); }
}

__global__ __launch_bounds__(NTHREADS) void rrt_kernel(
    const float* __restrict__ state, const float* __restrict__ goal,
    const float* __restrict__ u, const float* __restrict__ r,
    float* __restrict__ out, unsigned* __restrict__ ws) {
  // LDS union: scanner blocks stage nodes; block 0 small coordinator scratch.
  __shared__ __align__(16) union {
    struct { float2 nodes[7936]; u64 K[NWAVES]; } s;               // 63552 B
    struct { u64 qtmp[64]; u64 mask[NWAVES]; u64 fkT[4][64];
             float bd2[64]; } c;                                   //  2880 B
  } sh;

  u64* outU  = (u64*)out;               // node i at outU[i] (float2-packed)
  // MbufK: 4-slot ring of 64 tagged keys, LAG-4 (r8-verified protocol).
  // Scanner iter i writes slot i&3, tag i+132: M over [0..64(i+1)] vs chunk
  // (i+4)'s sample.  Coordinator merge j (>=4) requires tag == j+128
  // EXACTLY on a value loaded TWO chunks early (C_{j-2}); coords gathered
  // ONE chunk early (A_{j-1}).  Slot reuse (iter i+4) gated on Nb chunk
  // i+4, published only after merge j=i+4 consumed iter i's M.
  u64* MbufK = (u64*)(ws + 64);         // bytes 256..2303
  u64* Nb    = (u64*)(ws + 576);        // bytes 2304..67839
  // Nb[m] = node m+1, written ONCE; 0xAA poison is an impossible node value
  // (all nodes >= 0; 0xAAAAAAAA is negative).  Data IS the ready flag.

  const int tid  = threadIdx.x;
  const int wave = tid >> 6;
  const int lane = tid & 63;
  const int blk  = blockIdx.x;

  const float n0x = state[0], n0y = state[1];
  const float gx = goal[0],  gy = goal[1];

  if (blk == 0) {
    // ============ coordinator team: 8 waves, 4 barriers per chunk ==========
    if (tid < 256) ((u64*)sh.c.fkT)[tid] = KEY_MAX;   // init fold ring
    if (tid == 0) st_agent(&outU[0], packf2(n0x, n0y));   // node 0
    __syncthreads();

    // all waves hold rolling samples: s = chunk j, s1/s2 = chunks j+1/j+2
    float sx, sy, s1x, s1y, s2x, s2y;
    load_sample(u, r, gx, gy, lane, sx, sy);
    load_sample(u, r, gx, gy, NCHUNK + lane, s1x, s1y);
    load_sample(u, r, gx, gy, 2 * NCHUNK + lane, s2x, s2y);

    // wave-0 state: current q + 2-deep history (carry coords via bpermute),
    // pipelined M machinery (kvUse/wvUse for merge j+1, kvPend for j+2).
    float nx = 0.0f, ny = 0.0f, pnx = 0.0f, pny = 0.0f, ppnx = 0.0f, ppny = 0.0f;
    u64 kvUse = 0, kvPend = 0, wvUse = 0;

    for (int j = 0; j < NCHUNKS; ++j) {
      const int c = j * NCHUNK;

      // all waves: prefetch chunk j+3 sample (fold target 3; rotates to s2)
      float s3x = 0.0f, s3y = 0.0f;
      if (j + 3 < NCHUNKS)
        load_sample(u, r, gx, gy, (j + 3) * NCHUNK + lane, s3x, s3y);

      float bd2 = 0.0f;

      // ---- Phase A (wave 0): merge + steer + share; prep next merge ----
      if (wave == 0) {
        // carry: fkT slot j&3 holds min over chunks j-3..j-1 vs s_j
        // (atomicMin'd by D_{j-3}/D_{j-2}/D_{j-1}); clear for target j+4.
        const u64 carK = sh.c.fkT[j & 3][lane];
        sh.c.fkT[j & 3][lane] = KEY_MAX;

        u64 Mkey; float mx = n0x, my = n0y;
        if (j >= 4) {
          const unsigned want = (unsigned)(j + 128);
          if (!__all((int)(tagof(kvUse) == want))) {
            // rare fallback: live poll + dependent gather
            u64* slot = MbufK + (((unsigned)(j - 4)) & 3u) * 64;
            u64 kv;
            for (;;) {
              kv = ld_agent(&slot[lane]);
              if (__all((int)(tagof(kv) == want))) break;
              __builtin_amdgcn_s_sleep(1);
            }
            compiler_fence();
            kvUse = kv;
            const unsigned imf = (unsigned)kv & 0x1FFFu;
            wvUse = ld_agent(&Nb[(imf ? imf : 1u) - 1u]);
          }
          const unsigned midx = (unsigned)kvUse & 0x1FFFu;
          Mkey = (kvUse & 0xFFFFFFFF00000000ull) | (u64)midx;   // strip tag
          if (midx) { mx = lo32f(wvUse); my = hi32f(wvUse); }
        } else {
          // j<4: fkT covers chunks 0..j-1 entirely; node 0 explicit.
          Mkey = mkkey(dist2_rn(n0x, n0y, sx, sy), 0);
        }

        // carry-winner coords from q-history registers (chunks j-3..j-1)
        // via per-lane bpermute; garbage when carK==KEY_MAX (discarded).
        const unsigned ci = (unsigned)carK & 0x1FFFu;
        const int srcB = (((int)ci - 1) & 63) * 4;
        const int ch = ((int)ci - 1) >> 6;        // winner's chunk
        const float a0x = bpermf(srcB, nx),   a0y = bpermf(srcB, ny);
        const float a1x = bpermf(srcB, pnx),  a1y = bpermf(srcB, pny);
        const float a2x = bpermf(srcB, ppnx), a2y = bpermf(srcB, ppny);
        const float cx = (ch == j - 1) ? a0x : ((ch == j - 2) ? a1x : a2x);
        const float cy = (ch == j - 1) ? a0y : ((ch == j - 2) ? a1y : a2y);

        // merge: M range [0..64(j-3)] disjoint-below carry range -> u64
        // key-min is the exact lex argmin incl. tie-breaks.
        const bool cWin = (carK < Mkey);
        const u64 winK = cWin ? carK : Mkey;
        bd2 = hi32f(winK);
        const float wbx = cWin ? cx : mx;
        const float wby = cWin ? cy : my;

        // prep merge j+1: promote kvPend (loaded at C_{j-1}, ~1.5 chunks
        // after scanner publish) and issue the coords gather NOW -> a full
        // chunk of flight before consumption at A_{j+1}.
        if (j >= 3 && j + 1 < NCHUNKS) {
          kvUse = kvPend;
          const unsigned imn = (unsigned)kvUse & 0x1FFFu;
          wvUse = ld_agent(&Nb[(imn ? imn : 1u) - 1u]);
        }

        // q-history shift, then steer (verified math)
        ppnx = pnx; ppny = pny; pnx = nx; pny = ny;
        const float dirx = sub_rn(sx, wbx), diry = sub_rn(sy, wby);
        const float dist = __fsqrt_rn(add_rn(bd2, 1e-12f));
        const float scl = (dist > 5.0f) ? __fdiv_rn(5.0f, dist) : 1.0f;
        nx = add_rn(wbx, mul_rn(dirx, scl));
        ny = add_rn(wby, mul_rn(diry, scl));
        sh.c.qtmp[lane] = packf2(nx, ny);   // pre-pop q
        sh.c.bd2[lane] = bd2;               // post-merge bd2
      }
      __syncthreads();                      // B1: (q, bd2) shared

      // ---- Phase B (all waves): scan t-range [TPW*w, TPW*w+TPW) ----
      // Exactness as r9: bits from pre-pop q and post-merge bd2; pops
      // recheck exactly and re-add changed steps.
      {
        float qxl, qyl, bb;
        if (wave == 0) { qxl = nx; qyl = ny; bb = bd2; }
        else {
          const u64 qv = sh.c.qtmp[lane];
          qxl = lo32f(qv); qyl = hi32f(qv);
          bb = sh.c.bd2[lane];
        }
        unsigned mw = 0;
        const int t0 = wave * TPW;
        #pragma unroll
        for (int tt = 0; tt < TPW; ++tt) {
          const int t = t0 + tt;
          const float px = bcastf(qxl, t);
          const float py = bcastf(qyl, t);
          const float d = dist2_rn(px, py, sx, sy);
          const u64 bal = __ballot(d < bb);
          if (t < 63 && (bal >> (t + 1)) != 0ull) mw |= (1u << tt);
        }
        sh.c.mask[wave] = ((u64)mw) << (wave * TPW);
      }
      __syncthreads();                      // B2: masks ready

      // ---- Phase C (wave 0): pops (r9-exact) + publish; load kvPend ----
      if (wave == 0) {
        u64 cand = 0;
        #pragma unroll
        for (int w = 0; w < NWAVES; ++w) cand |= sh.c.mask[w];
        // kvPend for merge j+2 (slot (j-2)&3, tag j+130): published by
        // scanner iter j-2 during chunk j-1 -> landed by now.
        if (j >= 2 && j + 2 < NCHUNKS)
          kvPend = ld_agent(&MbufK[(((unsigned)(j - 2)) & 3u) * 64 + lane]);
        while (cand) {
          const int t = (int)__builtin_ctzll(cand);
          cand &= (cand - 1);
          const float px = bcastf(nx, t);
          const float py = bcastf(ny, t);
          const float d = dist2_rn(px, py, sx, sy);
          const bool upd = (lane > t) && (d < bd2);
          const u64 ub = __ballot(upd);
          if (ub != 0ull) {
            if (upd) {                  // exact sequential update body
              bd2 = d;
              const float dirx = sub_rn(sx, px), diry = sub_rn(sy, py);
              const float dist = __fsqrt_rn(add_rn(d, 1e-12f));
              const float scl = (dist > 5.0f) ? __fdiv_rn(5.0f, dist) : 1.0f;
              nx = add_rn(px, mul_rn(dirx, scl));
              ny = add_rn(py, mul_rn(diry, scl));
            }
            cand |= ub;                 // changed steps become candidates
          }
        }
        const u64 pv = packf2(nx, ny);
        st_agent(&outU[c + lane + 1], pv);
        st_agent(&Nb[c + lane], pv);
        sh.c.qtmp[lane] = pv;           // FINAL q for the folds
      }
      __syncthreads();                      // B3: final q ready

      // ---- Phase D (all waves): fold t-range vs s1/s2/s3 into fkT ring ----
      // atomicMin (ds_min_u64) combines across waves AND across the three
      // contributing chunks per target slot; (d2,idx) keys -> order-free
      // exact ties.  Slot T&3 is read+cleared at A_T.
      {
        float qfx, qfy;
        if (wave == 0) { qfx = nx; qfy = ny; }
        else { const u64 qv = sh.c.qtmp[lane]; qfx = lo32f(qv); qfy = hi32f(qv); }
        u64 k1 = KEY_MAX, k2 = KEY_MAX, k3 = KEY_MAX;
        const int t0 = wave * TPW;
        #pragma unroll
        for (int tt = 0; tt < TPW; ++tt) {
          const int t = t0 + tt;
          const float px = bcastf(qfx, t);
          const float py = bcastf(qfy, t);
          const int idx = c + t + 1;
          const u64 a1 = mkkey(dist2_rn(px, py, s1x, s1y), idx); if (a1 < k1) k1 = a1;
          const u64 a2 = mkkey(dist2_rn(px, py, s2x, s2y), idx); if (a2 < k2) k2 = a2;
          const u64 a3 = mkkey(dist2_rn(px, py, s3x, s3y), idx); if (a3 < k3) k3 = a3;
        }
        if (j + 1 < NCHUNKS) atomicMin(&sh.c.fkT[(j + 1) & 3][lane], k1);
        if (j + 2 < NCHUNKS) atomicMin(&sh.c.fkT[(j + 2) & 3][lane], k2);
        if (j + 3 < NCHUNKS) atomicMin(&sh.c.fkT[(j + 3) & 3][lane], k3);
      }
      __syncthreads();                      // B4: fold ring ready

      // all waves: rotate samples
      sx = s1x; sy = s1y; s1x = s2x; s1y = s2y; s2x = s3x; s2y = s3y;
    }
  } else {
    // ================= scanners: blocks 1..64, one sample each =============
    // LAG-4 (r8-verified): iter i (0..123): issue Nb load for chunk i;
    // bulk-scan [1..64i] from LDS + node 0 under it; wave-0 tail validates
    // fresh chunk i via the poison gate, stages + folds, publishes tag i+132
    // into ring slot i&3 (for merge j=i+4, vs chunk (i+4)'s sample).
    const int b = blk - 1;

    for (int i = 0; i < NCHUNKS - 4; ++i) {
      const int c = i * NCHUNK;

      u64 nv = POISON64;
      if (wave == 0) nv = ld_agent(&Nb[c + lane]);   // issue early, check late

      // my sample: chunk i+4, slot b
      float sx, sy;
      load_sample(u, r, gx, gy, (i + 4) * NCHUNK + b, sx, sy);

      // ---- bulk scan of staged nodes [1..64i] + node 0 ----
      u64 key = KEY_MAX;
      if (tid == 0) key = mkkey(dist2_rn(n0x, n0y, sx, sy), 0);
      // 512 lanes stride node pairs; float4 = nodes (jj, jj+1), jj odd
      for (int jj = 1 + 2 * tid; jj < c; jj += 2 * NTHREADS) {
        const float4 p = *(const float4*)&sh.s.nodes[jj - 1];
        const u64 ka = mkkey(dist2_rn(p.x, p.y, sx, sy), jj);
        const u64 kb = mkkey(dist2_rn(p.z, p.w, sx, sy), jj + 1);
        if (ka < key) key = ka;     // lower idx first: exact argmin ties
        if (kb < key) key = kb;
      }
      #pragma unroll
      for (int m = 32; m >= 1; m >>= 1) {
        const u64 ok = __shfl_xor(key, m, 64);
        if (ok < key) key = ok;
      }
      if (lane == 0) sh.s.K[wave] = key;
      __syncthreads();                  // barrier A: partials ready

      // ---- wave-0 tail: validate fresh chunk i, stage, fold, publish ----
      if (wave == 0) {
        u64 kk = (lane < NWAVES) ? sh.s.K[lane] : KEY_MAX;
        u64 ok = __shfl_xor(kk, 1, 64); if (ok < kk) kk = ok;
        ok = __shfl_xor(kk, 2, 64);     if (ok < kk) kk = ok;
        ok = __shfl_xor(kk, 4, 64);     if (ok < kk) kk = ok;

        while (!__all((int)(nv != POISON64))) {   // data arrival = signal
          __builtin_amdgcn_s_sleep(1);
          nv = ld_agent(&Nb[c + lane]);
        }
        compiler_fence();
        const float px = lo32f(nv), py = hi32f(nv);
        {
          float2 p; p.x = px; p.y = py;
          sh.s.nodes[c + lane] = p;       // stage chunk i for future bulks
          const u64 ki = mkkey(dist2_rn(px, py, sx, sy), c + lane + 1);
          if (ki < kk) kk = ki;           // (d2,idx) key: order-free ties
        }
        #pragma unroll
        for (int m = 32; m >= 1; m >>= 1) {
          const u64 o2 = __shfl_xor(kk, m, 64);
          if (o2 < kk) kk = o2;
        }
        if (lane == 0) {
          u64* slot = MbufK + (((unsigned)i) & 3u) * 64;
          st_agent(&slot[b], kk | ((u64)(unsigned)(i + 132) << 13));
        }
      }
      // barrier B: gates next iter's bulk reads of freshly staged nodes and
      // K reuse.
      __syncthreads();
    }
  }
}

extern "C" void kernel_launch(void* const* d_in, const int* in_sizes, int n_in,
                              void* d_out, int out_size, void* d_ws, size_t ws_size,
                              hipStream_t stream) {
  const float* state = (const float*)d_in[0];
  const float* goal  = (const float*)d_in[1];
  const float* u     = (const float*)d_in[2];
  const float* r     = (const float*)d_in[3];
  float* out = (float*)d_out;
  unsigned* ws = (unsigned*)d_ws;
  (void)in_sizes; (void)n_in; (void)out_size; (void)ws_size;
  rrt_kernel<<<NSCAN + 1, NTHREADS, 0, stream>>>(state, goal, u, r, out, ws);
}